// Round 13
// baseline (203.642 us; speedup 1.0000x reference)
//
#include <hip/hip_runtime.h>
#include <hip/hip_bf16.h>
#include <math.h>

#define NNODES 100000
#define FIN 500
#define KPAD 512
#define HIDDIM 64
#define NCLS 40
#define KORD 10
#define TILES 6250  // NNODES / 16

typedef __bf16 bf16x4 __attribute__((ext_vector_type(4)));
typedef __bf16 bf16x8 __attribute__((ext_vector_type(8)));
typedef float f32x4 __attribute__((ext_vector_type(4)));

// ---------------- polynomial coefficients + need-flags from temp ----------------
// out = sum_j C(K,j)/2^K * relu(temp[j]) * (I-A)^j (I+A)^{K-j} h = sum_m g[m] A^m h
// g[m] = sum_j s_j * T[j][m], T[j][m] = coeff of x^m in (1-x)^j (1+x)^{K-j}.
// All intermediates are integers/1024 with numerators < 2^24, exact in f32.
// flags[m] = 1 iff any g[j] != 0 for j >= m  (SpMV step m still needed).
__global__ void coeff_kernel(const float* __restrict__ temp, float* __restrict__ g,
                             int* __restrict__ flags) {
  if (threadIdx.x != 0 || blockIdx.x != 0) return;
  float C[KORD + 1][KORD + 1];
  for (int n = 0; n <= KORD; ++n)
    for (int k = 0; k <= KORD; ++k) C[n][k] = 0.f;
  for (int n = 0; n <= KORD; ++n) {
    C[n][0] = 1.f;
    for (int k = 1; k <= n; ++k) C[n][k] = C[n - 1][k - 1] + C[n - 1][k];
  }
  float s[KORD + 1];
  for (int j = 0; j <= KORD; ++j) {
    float th = temp[j] > 0.f ? temp[j] : 0.f;
    s[j] = C[KORD][j] * (1.0f / 1024.0f) * th;
  }
  for (int m = 0; m <= KORD; ++m) {
    float acc = 0.f;
    for (int j = 0; j <= KORD; ++j) {
      float T = 0.f;
      for (int a = 0; a <= m; ++a) {
        int b = m - a;
        if (a <= j && b <= KORD - j)
          T += ((a & 1) ? -1.f : 1.f) * C[j][a] * C[KORD - j][b];
      }
      acc += s[j] * T;
    }
    g[m] = acc;
  }
  int any = 0;
  flags[0] = 1;
  for (int m = KORD; m >= 1; --m) {
    if (g[m] != 0.f) any = 1;
    flags[m] = any;
  }
}

// ---------------- gated zero of CSR-build scratch ----------------
__global__ __launch_bounds__(256) void zero_kernel(int* __restrict__ p,
                                                   const int* __restrict__ flags,
                                                   int nwords) {
  if (flags[1] == 0) return;
  for (int i = blockIdx.x * 256 + threadIdx.x; i < nwords; i += gridDim.x * 256)
    p[i] = 0;
}

// ---------------- counts: out-degree at src + in-degree at dst ----------------
__global__ __launch_bounds__(256) void cnt_kernel(const int* __restrict__ src,
                                                  const int* __restrict__ dst,
                                                  int* __restrict__ deg_i,
                                                  int* __restrict__ cnt_dst,
                                                  const int* __restrict__ flags, int E) {
  if (flags[1] == 0) return;
  for (int e = blockIdx.x * 256 + threadIdx.x; e < E; e += gridDim.x * 256) {
    atomicAdd(&deg_i[src[e]], 1);
    atomicAdd(&cnt_dst[dst[e]], 1);
  }
}

__global__ __launch_bounds__(256) void dis_kernel(const int* __restrict__ deg_i,
                                                  float* __restrict__ dis,
                                                  const int* __restrict__ flags, int n) {
  if (flags[1] == 0) return;
  for (int i = blockIdx.x * 256 + threadIdx.x; i < n; i += gridDim.x * 256) {
    int d = deg_i[i];
    dis[i] = d > 0 ? 1.0f / sqrtf((float)d) : 0.f;
  }
}

// ---------------- exclusive prefix sum of cnt_dst -> rowptr[0..n] ----------------
__global__ __launch_bounds__(1024) void scan_kernel(const int* __restrict__ cnt,
                                                    int* __restrict__ rowptr,
                                                    const int* __restrict__ flags) {
  if (flags[1] == 0) return;
  __shared__ int part[1024];
  int t = threadIdx.x;
  const int chunk = (NNODES + 1023) / 1024;
  int lo = t * chunk, hi = lo + chunk;
  if (hi > NNODES) hi = NNODES;
  int s = 0;
  for (int i = lo; i < hi; ++i) s += cnt[i];
  part[t] = s;
  __syncthreads();
  for (int off = 1; off < 1024; off <<= 1) {
    int v = (t >= off) ? part[t - off] : 0;
    __syncthreads();
    part[t] += v;
    __syncthreads();
  }
  int run = (t > 0) ? part[t - 1] : 0;
  for (int i = lo; i < hi; ++i) {
    rowptr[i] = run;
    run += cnt[i];
  }
  if (t == 1023) rowptr[NNODES] = run;
}

// ---------------- CSR fill (dst-major): col[pos] = src ----------------
__global__ __launch_bounds__(256) void fill_kernel(const int* __restrict__ src,
                                                   const int* __restrict__ dst,
                                                   const int* __restrict__ rowptr,
                                                   int* __restrict__ tmpc,
                                                   int* __restrict__ col,
                                                   const int* __restrict__ flags, int E) {
  if (flags[1] == 0) return;
  for (int e = blockIdx.x * 256 + threadIdx.x; e < E; e += gridDim.x * 256) {
    int d = dst[e];
    int pos = rowptr[d] + atomicAdd(&tmpc[d], 1);
    col[pos] = src[e];
  }
}

// ---------------- W1 -> fragment-major bf16 (w1p) ----------------
// Fragment f = c*4 + ct (k-chunk c, col-chunk ct), lane l, elem i:
// w1p[f*512 + l*8 + i] = bf16(W1[c*32 + (l>>4)*8 + i][ct*16 + (l&15)]), 0 if k>=500.
// gemm1's B-load for (c,ct) is then ONE lane-contiguous 1 KB wave-instr.
__global__ __launch_bounds__(256) void w1p_kernel(const float* __restrict__ W1,
                                                  __bf16* __restrict__ w1p) {
  int idx = blockIdx.x * 256 + threadIdx.x;  // (f, lane) pair, 4096 total
  if (idx >= 4096) return;
  int f = idx >> 6, l = idx & 63;
  int c = f >> 2, ct = f & 3;
  int col = ct * 16 + (l & 15);
  int kb = c * 32 + (l >> 4) * 8;
  bf16x8 v;
#pragma unroll
  for (int i = 0; i < 8; ++i) {
    int k = kb + i;
    v[i] = (k < FIN) ? (__bf16)W1[(size_t)k * HIDDIM + col] : (__bf16)0.f;
  }
  *(bf16x8*)(w1p + (size_t)f * 512 + l * 8) = v;
}

// ---------------- pack: x (f32 row-major) -> xpk (bf16, MFMA-fragment-major) ----------------
// Tile = 16 rows. For tile T, chunk c (32 k), lane l: xpk[T*8192 + c*512 + l*8 .. +7]
// = bf16(x[T*16 + (l&15)][c*32 + (l>>4)*8 .. +7]), zeros for k >= 500.
// Both the x read and the xpk write are 1 KB-contiguous per wave-instr.
__global__ __launch_bounds__(256) void pack_kernel(const float* __restrict__ x,
                                                   __bf16* __restrict__ xpk) {
  __shared__ float lds[16][516];  // pitch 516: <=2-way bank conflicts
  const int tile = blockIdx.x;
  const int t = threadIdx.x;
  const float4* xs = (const float4*)(x + (size_t)tile * 8000);
  for (int j = t; j < 2000; j += 256) {  // 16 rows * 125 float4, coalesced
    float4 q = xs[j];
    int row = j / 125, c4 = j - row * 125;
    *(float4*)&lds[row][c4 * 4] = q;
  }
  lds[t >> 4][500 + (t & 15)] = 0.f;  // zero k = 500..515
  __syncthreads();

  const int w = t >> 6, lane = t & 63;
  const int r = lane & 15, kq = lane >> 4;
#pragma unroll
  for (int i = 0; i < 4; ++i) {
    int c = i * 4 + w;
    int cc = c * 32 + kq * 8;
    float4 a0 = *(const float4*)&lds[r][cc];
    float4 a1 = *(const float4*)&lds[r][cc + 4];
    bf16x8 v;
    v[0] = (__bf16)a0.x; v[1] = (__bf16)a0.y; v[2] = (__bf16)a0.z; v[3] = (__bf16)a0.w;
    v[4] = (__bf16)a1.x; v[5] = (__bf16)a1.y; v[6] = (__bf16)a1.z; v[7] = (__bf16)a1.w;
    *(bf16x8*)(xpk + (size_t)tile * 8192 + c * 512 + lane * 8) = v;
  }
}

// ---------------- fused MLP: u = relu(x@W1+b1)@W2+b2 ; out = g0*u ----------------
// NO LDS in the MFMA loop, no barriers before it: A from xpk (depth-4 contiguous
// ring), B from w1p (L2-hot, 1 KB-contiguous per instr). LDS holds only the
// epilogue arena (46 KB) -> 3 blocks x 8 waves = 24 waves/CU.
__global__ __launch_bounds__(512, 6) void gemm1_kernel(
    const __bf16* __restrict__ xpk, const __bf16* __restrict__ w1p,
    const float* __restrict__ b1, const float* __restrict__ W2,
    const float* __restrict__ b2, const float* __restrict__ g,
    float* __restrict__ u, float* __restrict__ out, int n) {
  __shared__ __align__(16) char arena[47104];
  const int t = threadIdx.x;
  const int w = t >> 6, lane = t & 63;
  const int arow = lane & 15;  // C/D col index component
  const int kq = lane >> 4;    // k quarter
  const int T = blockIdx.x * 8 + w;
  f32x4 acc[4] = {};

  if (T < TILES) {
    const __bf16* abase = xpk + (size_t)T * 8192 + lane * 8;
    const __bf16* bbase = w1p + lane * 8;
    bf16x8 a0 = *(const bf16x8*)(abase);
    bf16x8 a1 = *(const bf16x8*)(abase + 512);
    bf16x8 a2 = *(const bf16x8*)(abase + 1024);
    bf16x8 a3 = *(const bf16x8*)(abase + 1536);

#define DO_CHUNK(c_, R)                                                           \
  {                                                                               \
    _Pragma("unroll") for (int ct = 0; ct < 4; ++ct) {                            \
      bf16x8 b = *(const bf16x8*)(bbase + (((c_) * 4 + ct) << 9));                \
      acc[ct] = __builtin_amdgcn_mfma_f32_16x16x32_bf16(R, b, acc[ct], 0, 0, 0);  \
    }                                                                             \
  }
    DO_CHUNK(0, a0)  a0 = *(const bf16x8*)(abase + 4 * 512);
    DO_CHUNK(1, a1)  a1 = *(const bf16x8*)(abase + 5 * 512);
    DO_CHUNK(2, a2)  a2 = *(const bf16x8*)(abase + 6 * 512);
    DO_CHUNK(3, a3)  a3 = *(const bf16x8*)(abase + 7 * 512);
    DO_CHUNK(4, a0)  a0 = *(const bf16x8*)(abase + 8 * 512);
    DO_CHUNK(5, a1)  a1 = *(const bf16x8*)(abase + 9 * 512);
    DO_CHUNK(6, a2)  a2 = *(const bf16x8*)(abase + 10 * 512);
    DO_CHUNK(7, a3)  a3 = *(const bf16x8*)(abase + 11 * 512);
    DO_CHUNK(8, a0)  a0 = *(const bf16x8*)(abase + 12 * 512);
    DO_CHUNK(9, a1)  a1 = *(const bf16x8*)(abase + 13 * 512);
    DO_CHUNK(10, a2) a2 = *(const bf16x8*)(abase + 14 * 512);
    DO_CHUNK(11, a3) a3 = *(const bf16x8*)(abase + 15 * 512);
    DO_CHUNK(12, a0)
    DO_CHUNK(13, a1)
    DO_CHUNK(14, a2)
    DO_CHUNK(15, a3)
#undef DO_CHUNK
  }
  __syncthreads();  // epilogue arena becomes valid for all waves

  // epilogue: hs = relu(acc + b1) -> LDS [128][66]; w2s copy; GEMM2; out = g0*u
  float* hs = (float*)arena;              // 128*66*4 = 33792 B
  float* w2s = (float*)(arena + 36864);   // 64*40*4 = 10240 B
  for (int i = t; i < HIDDIM * NCLS; i += 512) w2s[i] = W2[i];
  {
#pragma unroll
    for (int ct = 0; ct < 4; ++ct) {
      float bv = b1[ct * 16 + arow];  // C/D col = lane&15
#pragma unroll
      for (int reg = 0; reg < 4; ++reg) {
        int rrow = w * 16 + kq * 4 + reg;  // C/D row = (lane>>4)*4 + reg
        float v = acc[ct][reg] + bv;
        hs[rrow * 66 + ct * 16 + arow] = v > 0.f ? v : 0.f;
      }
    }
  }
  __syncthreads();

  int row = t >> 2, cg = (t & 3) * 10;  // 128 rows x 4 col-groups
  float o[10] = {};
  for (int k = 0; k < HIDDIM; ++k) {
    float a = hs[row * 66 + k];
#pragma unroll
    for (int j = 0; j < 10; ++j) o[j] += a * w2s[k * 40 + cg + j];
  }
  int gr2 = blockIdx.x * 128 + row;
  if (gr2 < n) {
    float g0 = g[0];
    float* urow = u + (size_t)gr2 * NCLS + cg;
    float* orow = out + (size_t)gr2 * NCLS + cg;
#pragma unroll
    for (int j = 0; j < 10; ++j) {
      float val = o[j] + b2[cg + j];
      urow[j] = val;
      orow[j] = g0 * val;
    }
  }
}

// ---------------- SpMV step m: uout = D^-1/2 A D^-1/2 uin ; out += g[m]*uout ----------------
// Wave per node (grid-stride); lanes 0..39 own feature columns. Matches reference
// associativity: sum over edges of (dis[src]*uin[src]), then * dis[dst].
__global__ __launch_bounds__(256) void spmv_kernel(
    const int* __restrict__ col, const int* __restrict__ rowptr,
    const float* __restrict__ dis, const float* __restrict__ uin,
    float* __restrict__ uout, float* __restrict__ out, const float* __restrict__ g,
    const int* __restrict__ flags, int m) {
  if (flags[m] == 0) return;
  int lane = threadIdx.x & 63;
  if (lane >= NCLS) return;
  int stride = gridDim.x * 4;
  for (int wid = blockIdx.x * 4 + (threadIdx.x >> 6); wid < NNODES; wid += stride) {
    int lo = rowptr[wid], hi = rowptr[wid + 1];
    float acc = 0.f;
    for (int e = lo; e < hi; ++e) {
      int s = col[e];
      acc += dis[s] * uin[(size_t)s * NCLS + lane];
    }
    acc *= dis[wid];
    size_t idx = (size_t)wid * NCLS + lane;
    uout[idx] = acc;
    out[idx] += g[m] * acc;
  }
}

// ---------------- log_softmax: one 64-lane wave per row (grid-stride) ----------------
__global__ __launch_bounds__(256) void lsm_kernel(const float* __restrict__ out,
                                                  float* __restrict__ lsm, int n) {
  int lane = threadIdx.x & 63;
  int stride = gridDim.x * 4;
  for (int wid = blockIdx.x * 4 + (threadIdx.x >> 6); wid < n; wid += stride) {
    float xv = (lane < NCLS) ? out[(size_t)wid * NCLS + lane] : -INFINITY;
    float mx = xv;
#pragma unroll
    for (int off = 32; off; off >>= 1) mx = fmaxf(mx, __shfl_xor(mx, off));
    float e = (lane < NCLS) ? expf(xv - mx) : 0.f;
    float sum = e;
#pragma unroll
    for (int off = 32; off; off >>= 1) sum += __shfl_xor(sum, off);
    float lse = logf(sum);
    if (lane < NCLS) lsm[(size_t)wid * NCLS + lane] = xv - mx - lse;
  }
}

extern "C" void kernel_launch(void* const* d_in, const int* in_sizes, int n_in,
                              void* d_out, int out_size, void* d_ws, size_t ws_size,
                              hipStream_t stream) {
  (void)n_in; (void)out_size; (void)ws_size;
  const float* x = (const float*)d_in[0];
  const int* ei = (const int*)d_in[1];
  const float* W1 = (const float*)d_in[2];
  const float* b1 = (const float*)d_in[3];
  const float* W2 = (const float*)d_in[4];
  const float* b2 = (const float*)d_in[5];
  const float* temp = (const float*)d_in[6];
  int E = in_sizes[1] / 2;
  const int* src = ei;
  const int* dst = ei + E;
  int n = NNODES;

  // ws layout in 4-byte words; total ~33.4M words (~134 MB)
  float* ws = (float*)d_ws;
  float* ua = ws;                          // 4,000,000 f32
  int* col = (int*)(ws + 4000000);         // 3,200,000 i32
  int* cnt_dst = (int*)(ws + 7200000);     // 100,000 i32 (zero_kernel covers this + next two)
  int* tmpc = (int*)(ws + 7300000);        // 100,000 i32
  int* deg_i = (int*)(ws + 7400000);       // 100,000 i32
  int* rowptr = (int*)(ws + 7500000);      // 100,001 i32
  float* dis = ws + 7600016;               // 100,000 f32
  float* g = ws + 7700016;                 // 16 f32
  int* flags = (int*)(ws + 7700032);       // 16 i32
  __bf16* w1p = (__bf16*)(ws + 7700048);   // 32,768 bf16 = 16,384 words
  __bf16* xpk = (__bf16*)(ws + 7716448);   // 51,200,000 bf16 = 25,600,000 words

  float* lsm = (float*)d_out;            // n*40, also ping-pong scratch during prop
  float* out = (float*)d_out + 4000000;  // n*40 accumulator, final output 1

  coeff_kernel<<<1, 64, 0, stream>>>(temp, g, flags);
  zero_kernel<<<32, 256, 0, stream>>>(cnt_dst, flags, 300000);
  cnt_kernel<<<96, 256, 0, stream>>>(src, dst, deg_i, cnt_dst, flags, E);
  dis_kernel<<<48, 256, 0, stream>>>(deg_i, dis, flags, n);
  scan_kernel<<<1, 1024, 0, stream>>>(cnt_dst, rowptr, flags);
  fill_kernel<<<96, 256, 0, stream>>>(src, dst, rowptr, tmpc, col, flags, E);
  w1p_kernel<<<16, 256, 0, stream>>>(W1, w1p);
  pack_kernel<<<TILES, 256, 0, stream>>>(x, xpk);
  gemm1_kernel<<<(TILES + 7) / 8, 512, 0, stream>>>(xpk, w1p, b1, W2, b2, g, ua, out, n);
  for (int m = 1; m <= KORD; ++m) {
    float* uin = (m & 1) ? ua : lsm;
    float* uout = (m & 1) ? lsm : ua;
    spmv_kernel<<<128, 256, 0, stream>>>(col, rowptr, dis, uin, uout, out, g, flags, m);
  }
  lsm_kernel<<<768, 256, 0, stream>>>(out, lsm, n);
}

// Round 14
// 134.410 us; speedup vs baseline: 1.5151x; 1.5151x over previous
//
#include <hip/hip_runtime.h>
#include <hip/hip_bf16.h>
#include <math.h>

#define NNODES 100000
#define FIN 500
#define KPAD 512
#define HIDDIM 64
#define NCLS 40
#define KORD 10

typedef __bf16 bf16x4 __attribute__((ext_vector_type(4)));
typedef __bf16 bf16x8 __attribute__((ext_vector_type(8)));
typedef float f32x4 __attribute__((ext_vector_type(4)));

// ---------------- device-scope grid barrier (two-variable, epoch-based) ----------------
// Valid only when all blocks are co-resident (grid <= 256 blocks here) and every
// block calls it with the same epoch sequence. arrive/epoch zeroed by prep_kernel.
__device__ __forceinline__ void gbar(unsigned* arrive, unsigned* epoch, int nblk,
                                     unsigned e) {
  __syncthreads();
  if (threadIdx.x == 0) {
    __threadfence();  // make this block's prior writes device-visible
    unsigned old = atomicAdd(arrive, 1u);
    if (old == (unsigned)nblk - 1u) {
      *arrive = 0u;  // safe: all other blocks spin on epoch until the exch below
      __threadfence();
      atomicExch(epoch, e);  // release
    } else {
      while (__hip_atomic_load(epoch, __ATOMIC_ACQUIRE, __HIP_MEMORY_SCOPE_AGENT) < e) {
        __builtin_amdgcn_s_sleep(8);
      }
    }
    __threadfence();
  }
  __syncthreads();
}

// ---------------- prep: w1t pack (blocks 0-15) + coeff/flags/barrier-init (block 16) ----
// coeff: out = sum_m g[m] A^m h with g derived exactly (dyadic rationals < 2^24).
// flags[m] = 1 iff any g[j] != 0 for j >= m.
__global__ __launch_bounds__(256) void prep_kernel(const float* __restrict__ W1,
                                                   __bf16* __restrict__ w1t,
                                                   const float* __restrict__ temp,
                                                   float* __restrict__ g,
                                                   int* __restrict__ flags,
                                                   unsigned* __restrict__ arrive,
                                                   unsigned* __restrict__ epoch) {
  if (blockIdx.x == 16) {
    if (threadIdx.x != 0) return;
    *arrive = 0u;
    *epoch = 0u;
    float C[KORD + 1][KORD + 1];
    for (int n = 0; n <= KORD; ++n)
      for (int k = 0; k <= KORD; ++k) C[n][k] = 0.f;
    for (int n = 0; n <= KORD; ++n) {
      C[n][0] = 1.f;
      for (int k = 1; k <= n; ++k) C[n][k] = C[n - 1][k - 1] + C[n - 1][k];
    }
    float s[KORD + 1];
    for (int j = 0; j <= KORD; ++j) {
      float th = temp[j] > 0.f ? temp[j] : 0.f;
      s[j] = C[KORD][j] * (1.0f / 1024.0f) * th;
    }
    for (int m = 0; m <= KORD; ++m) {
      float acc = 0.f;
      for (int j = 0; j <= KORD; ++j) {
        float T = 0.f;
        for (int a = 0; a <= m; ++a) {
          int b = m - a;
          if (a <= j && b <= KORD - j)
            T += ((a & 1) ? -1.f : 1.f) * C[j][a] * C[KORD - j][b];
        }
        acc += s[j] * T;
      }
      g[m] = acc;
    }
    int any = 0;
    flags[0] = 1;
    for (int m = KORD; m >= 1; --m) {
      if (g[m] != 0.f) any = 1;
      flags[m] = any;
    }
    return;
  }
  // blocks 0..15: W1 -> transposed bf16, K padded to 512: w1t[c][k]
  for (int idx = blockIdx.x * 256 + threadIdx.x; idx < HIDDIM * KPAD; idx += 16 * 256) {
    int c = idx >> 9, k = idx & (KPAD - 1);
    float v = (k < FIN) ? W1[(size_t)k * HIDDIM + c] : 0.f;
    w1t[(size_t)c * KPAD + k] = (__bf16)v;
  }
}

// ---------------- fused MLP: u = relu(x@W1+b1)@W2+b2 ; out = g0*u ----------------
// R10 kernel, unchanged (best measured: ~115 us). Free-running waves + depth-4
// register prefetch ring; w1t in LDS (XOR-swizzled); epilogue GEMM2 via LDS.
__global__ __launch_bounds__(512, 4) void mlp_kernel(
    const float* __restrict__ x, const __bf16* __restrict__ w1t,
    const float* __restrict__ b1, const float* __restrict__ W2,
    const float* __restrict__ b2, const float* __restrict__ g,
    float* __restrict__ u, float* __restrict__ out, int n) {
  __shared__ __align__(16) char arena[65536];
  const int t = threadIdx.x;
  const int w = t >> 6, lane = t & 63;
  const int row0 = blockIdx.x * 128;

#pragma unroll
  for (int i = 0; i < 8; ++i) {
    int id = t + 512 * i;  // 16B chunk id, 0..4095
    int c = id >> 6, unit = id & 63;
    bf16x8 v = *(const bf16x8*)(w1t + (size_t)id * 8);
    *(bf16x8*)(arena + c * 1024 + ((unit ^ (c & 7)) << 4)) = v;
  }
  __syncthreads();

  const int arow = lane & 15;
  const int kq = lane >> 4;
  int gr = row0 + w * 16 + arow;
  if (gr > NNODES - 1) gr = NNODES - 1;
  const float* xrow = x + (size_t)gr * FIN + kq * 8;

  f32x4 acc[4] = {};
  float4 s0a, s0b, s1a, s1b, s2a, s2b, s3a, s3b;
#define LOAD_PLAIN(A, B, c_)              \
  A = *(const float4*)(xrow + (c_) * 32); \
  B = *(const float4*)(xrow + (c_) * 32 + 4);
#define LOAD_TAIL(A, B)              \
  {                                  \
    A = *(const float4*)(xrow + 480);\
    B = *(const float4*)(xrow + 484);\
    int kb = 480 + kq * 8;           \
    if (kb + 0 >= FIN) A.x = 0.f;    \
    if (kb + 1 >= FIN) A.y = 0.f;    \
    if (kb + 2 >= FIN) A.z = 0.f;    \
    if (kb + 3 >= FIN) A.w = 0.f;    \
    if (kb + 4 >= FIN) B.x = 0.f;    \
    if (kb + 5 >= FIN) B.y = 0.f;    \
    if (kb + 6 >= FIN) B.z = 0.f;    \
    if (kb + 7 >= FIN) B.w = 0.f;    \
  }
  LOAD_PLAIN(s0a, s0b, 0)
  LOAD_PLAIN(s1a, s1b, 1)
  LOAD_PLAIN(s2a, s2b, 2)
  LOAD_PLAIN(s3a, s3b, 3)

#define DO_CHUNK(c_, QA, QB)                                                      \
  {                                                                               \
    bf16x8 a;                                                                     \
    a[0] = (__bf16)QA.x; a[1] = (__bf16)QA.y; a[2] = (__bf16)QA.z;                \
    a[3] = (__bf16)QA.w; a[4] = (__bf16)QB.x; a[5] = (__bf16)QB.y;                \
    a[6] = (__bf16)QB.z; a[7] = (__bf16)QB.w;                                     \
    int uu = (c_) * 4 + kq;                                                       \
    _Pragma("unroll") for (int ct = 0; ct < 4; ++ct) {                            \
      int col = ct * 16 + arow;                                                   \
      bf16x8 b = *(const bf16x8*)(arena + col * 1024 + ((uu ^ (col & 7)) << 4));  \
      acc[ct] = __builtin_amdgcn_mfma_f32_16x16x32_bf16(a, b, acc[ct], 0, 0, 0);  \
    }                                                                             \
  }

  DO_CHUNK(0, s0a, s0b)  LOAD_PLAIN(s0a, s0b, 4)
  DO_CHUNK(1, s1a, s1b)  LOAD_PLAIN(s1a, s1b, 5)
  DO_CHUNK(2, s2a, s2b)  LOAD_PLAIN(s2a, s2b, 6)
  DO_CHUNK(3, s3a, s3b)  LOAD_PLAIN(s3a, s3b, 7)
  DO_CHUNK(4, s0a, s0b)  LOAD_PLAIN(s0a, s0b, 8)
  DO_CHUNK(5, s1a, s1b)  LOAD_PLAIN(s1a, s1b, 9)
  DO_CHUNK(6, s2a, s2b)  LOAD_PLAIN(s2a, s2b, 10)
  DO_CHUNK(7, s3a, s3b)  LOAD_PLAIN(s3a, s3b, 11)
  DO_CHUNK(8, s0a, s0b)  LOAD_PLAIN(s0a, s0b, 12)
  DO_CHUNK(9, s1a, s1b)  LOAD_PLAIN(s1a, s1b, 13)
  DO_CHUNK(10, s2a, s2b) LOAD_PLAIN(s2a, s2b, 14)
  DO_CHUNK(11, s3a, s3b) LOAD_TAIL(s3a, s3b)
  DO_CHUNK(12, s0a, s0b)
  DO_CHUNK(13, s1a, s1b)
  DO_CHUNK(14, s2a, s2b)
  DO_CHUNK(15, s3a, s3b)
#undef DO_CHUNK
#undef LOAD_PLAIN
#undef LOAD_TAIL

  __syncthreads();  // all w1t LDS reads done; arena reused below

  float* hs = (float*)arena;             // [128][66]
  float* w2s = (float*)(arena + 36864);  // [64][40]
  for (int i = t; i < HIDDIM * NCLS; i += 512) w2s[i] = W2[i];
  {
#pragma unroll
    for (int ct = 0; ct < 4; ++ct) {
      float bv = b1[ct * 16 + arow];
#pragma unroll
      for (int reg = 0; reg < 4; ++reg) {
        int rrow = w * 16 + kq * 4 + reg;
        float v = acc[ct][reg] + bv;
        hs[rrow * 66 + ct * 16 + arow] = v > 0.f ? v : 0.f;
      }
    }
  }
  __syncthreads();

  int row = t >> 2, cg = (t & 3) * 10;
  float o[10] = {};
  for (int k = 0; k < HIDDIM; ++k) {
    float a = hs[row * 66 + k];
#pragma unroll
    for (int j = 0; j < 10; ++j) o[j] += a * w2s[k * 40 + cg + j];
  }
  int gr2 = row0 + row;
  if (gr2 < n) {
    float g0 = g[0];
    float* urow = u + (size_t)gr2 * NCLS + cg;
    float* orow = out + (size_t)gr2 * NCLS + cg;
#pragma unroll
    for (int j = 0; j < 10; ++j) {
      float val = o[j] + b2[cg + j];
      urow[j] = val;
      orow[j] = g0 * val;
    }
  }
}

// ---------------- fused propagation: CSR build + 10 SpMV steps, one launch ----------------
// All blocks co-resident (208 <= 256 CUs); grid barriers sequence the phases.
// Null path (flags[1]==0, the benchmark case): immediate uniform return, no barriers.
__global__ __launch_bounds__(256) void prop_kernel(
    const int* __restrict__ src, const int* __restrict__ dst, int E,
    int* __restrict__ cnt_dst, int* __restrict__ tmpc, int* __restrict__ deg_i,
    int* __restrict__ rowptr, int* __restrict__ col, float* __restrict__ dis,
    float* __restrict__ ua, float* __restrict__ lsm, float* __restrict__ out,
    const float* __restrict__ g, const int* __restrict__ flags,
    unsigned* __restrict__ arrive, unsigned* __restrict__ epoch) {
  if (flags[1] == 0) return;
  const int t = threadIdx.x;
  const int nb = gridDim.x;
  const int gid = blockIdx.x * 256 + t;
  const int gstride = nb * 256;
  unsigned e = 0;

  // phase 0: zero cnt_dst/tmpc/deg_i (contiguous 300000 ints)
  for (int i = gid; i < 300000; i += gstride) cnt_dst[i] = 0;
  gbar(arrive, epoch, nb, ++e);

  // phase 1: degree counts
  for (int ed = gid; ed < E; ed += gstride) {
    atomicAdd(&deg_i[src[ed]], 1);
    atomicAdd(&cnt_dst[dst[ed]], 1);
  }
  gbar(arrive, epoch, nb, ++e);

  // phase 2: dis (all blocks) + exclusive scan -> rowptr (block 0)
  for (int i = gid; i < NNODES; i += gstride) {
    int d = deg_i[i];
    dis[i] = d > 0 ? 1.0f / sqrtf((float)d) : 0.f;
  }
  if (blockIdx.x == 0) {
    __shared__ int part[256];
    const int chunk = (NNODES + 255) / 256;  // 391
    int lo = t * chunk, hi = lo + chunk;
    if (hi > NNODES) hi = NNODES;
    int s = 0;
    for (int i = lo; i < hi; ++i) s += cnt_dst[i];
    part[t] = s;
    __syncthreads();
    for (int off = 1; off < 256; off <<= 1) {
      int v = (t >= off) ? part[t - off] : 0;
      __syncthreads();
      part[t] += v;
      __syncthreads();
    }
    int run = (t > 0) ? part[t - 1] : 0;
    for (int i = lo; i < hi; ++i) {
      rowptr[i] = run;
      run += cnt_dst[i];
    }
    if (t == 255) rowptr[NNODES] = run;
  }
  gbar(arrive, epoch, nb, ++e);

  // phase 3: CSR fill (dst-major)
  for (int ed = gid; ed < E; ed += gstride) {
    int d = dst[ed];
    int pos = rowptr[d] + atomicAdd(&tmpc[d], 1);
    col[pos] = src[ed];
  }
  gbar(arrive, epoch, nb, ++e);

  // phases 4..: SpMV steps m = 1..KORD, wave per node, lanes 0..39 = features
  const int lane = t & 63;
  const int wid0 = blockIdx.x * 4 + (t >> 6);
  const int wstride = nb * 4;
  for (int m = 1; m <= KORD; ++m) {
    if (flags[m] == 0) break;  // uniform across device
    float* uin = (m & 1) ? ua : lsm;
    float* uout = (m & 1) ? lsm : ua;
    if (lane < NCLS) {
      float gm = g[m];
      for (int wid = wid0; wid < NNODES; wid += wstride) {
        int lo = rowptr[wid], hi = rowptr[wid + 1];
        float acc = 0.f;
        for (int ee = lo; ee < hi; ++ee) {
          int s = col[ee];
          acc += dis[s] * uin[(size_t)s * NCLS + lane];
        }
        acc *= dis[wid];
        size_t idx = (size_t)wid * NCLS + lane;
        uout[idx] = acc;
        out[idx] += gm * acc;
      }
    }
    if (m < KORD) gbar(arrive, epoch, nb, ++e);
  }
}

// ---------------- log_softmax: one 64-lane wave per row (grid-stride) ----------------
__global__ __launch_bounds__(256) void lsm_kernel(const float* __restrict__ out,
                                                  float* __restrict__ lsm, int n) {
  int lane = threadIdx.x & 63;
  int stride = gridDim.x * 4;
  for (int wid = blockIdx.x * 4 + (threadIdx.x >> 6); wid < n; wid += stride) {
    float xv = (lane < NCLS) ? out[(size_t)wid * NCLS + lane] : -INFINITY;
    float mx = xv;
#pragma unroll
    for (int off = 32; off; off >>= 1) mx = fmaxf(mx, __shfl_xor(mx, off));
    float e = (lane < NCLS) ? expf(xv - mx) : 0.f;
    float sum = e;
#pragma unroll
    for (int off = 32; off; off >>= 1) sum += __shfl_xor(sum, off);
    float lse = logf(sum);
    if (lane < NCLS) lsm[(size_t)wid * NCLS + lane] = xv - mx - lse;
  }
}

extern "C" void kernel_launch(void* const* d_in, const int* in_sizes, int n_in,
                              void* d_out, int out_size, void* d_ws, size_t ws_size,
                              hipStream_t stream) {
  (void)n_in; (void)out_size; (void)ws_size;
  const float* x = (const float*)d_in[0];
  const int* ei = (const int*)d_in[1];
  const float* W1 = (const float*)d_in[2];
  const float* b1 = (const float*)d_in[3];
  const float* W2 = (const float*)d_in[4];
  const float* b2 = (const float*)d_in[5];
  const float* temp = (const float*)d_in[6];
  int E = in_sizes[1] / 2;
  const int* src = ei;
  const int* dst = ei + E;
  int n = NNODES;

  // ws layout in 4-byte words; total ~7.72M words (~30.9 MB)
  float* ws = (float*)d_ws;
  float* ua = ws;                             // 4,000,000 f32
  int* col = (int*)(ws + 4000000);            // 3,200,000 i32
  int* cnt_dst = (int*)(ws + 7200000);        // 100,000 i32 (zeroed with next two)
  int* tmpc = (int*)(ws + 7300000);           // 100,000 i32
  int* deg_i = (int*)(ws + 7400000);          // 100,000 i32
  int* rowptr = (int*)(ws + 7500000);         // 100,001 i32
  float* dis = ws + 7600016;                  // 100,000 f32
  float* g = ws + 7700016;                    // 16 f32
  int* flags = (int*)(ws + 7700032);          // 16 i32
  unsigned* arrive = (unsigned*)(ws + 7700048);  // 1 u32
  unsigned* epoch = (unsigned*)(ws + 7700049);  // 1 u32
  __bf16* w1t = (__bf16*)(ws + 7700064);      // 32,768 bf16 = 16,384 words

  float* lsm = (float*)d_out;            // n*40, also ping-pong scratch during prop
  float* out = (float*)d_out + 4000000;  // n*40 accumulator, final output 1

  prep_kernel<<<17, 256, 0, stream>>>(W1, w1t, temp, g, flags, arrive, epoch);
  mlp_kernel<<<(n + 127) / 128, 512, 0, stream>>>(x, w1t, b1, W2, b2, g, ua, out, n);
  prop_kernel<<<208, 256, 0, stream>>>(src, dst, E, cnt_dst, tmpc, deg_i, rowptr, col,
                                       dis, ua, lsm, out, g, flags, arrive, epoch);
  lsm_kernel<<<768, 256, 0, stream>>>(out, lsm, n);
}

// Round 15
// 107.784 us; speedup vs baseline: 1.8894x; 1.2470x over previous
//
#include <hip/hip_runtime.h>
#include <hip/hip_bf16.h>
#include <math.h>

#define NNODES 100000
#define FIN 500
#define KPAD 512
#define HIDDIM 64
#define NCLS 40
#define KORD 10

typedef __bf16 bf16x4 __attribute__((ext_vector_type(4)));
typedef __bf16 bf16x8 __attribute__((ext_vector_type(8)));
typedef float f32x4 __attribute__((ext_vector_type(4)));

// ---------------- device-scope grid barrier (two-variable, epoch-based) ----------------
// Valid only when all blocks are co-resident (grid <= 256 blocks here) and every
// block calls it with the same epoch sequence. arrive/epoch zeroed by prep_kernel.
__device__ __forceinline__ void gbar(unsigned* arrive, unsigned* epoch, int nblk,
                                     unsigned e) {
  __syncthreads();
  if (threadIdx.x == 0) {
    __threadfence();  // make this block's prior writes device-visible
    unsigned old = atomicAdd(arrive, 1u);
    if (old == (unsigned)nblk - 1u) {
      *arrive = 0u;  // safe: all other blocks spin on epoch until the exch below
      __threadfence();
      atomicExch(epoch, e);  // release
    } else {
      while (__hip_atomic_load(epoch, __ATOMIC_ACQUIRE, __HIP_MEMORY_SCOPE_AGENT) < e) {
        __builtin_amdgcn_s_sleep(8);
      }
    }
    __threadfence();
  }
  __syncthreads();
}

// ---------------- prep: w1t pack (blocks 0-15) + coeff/flags/barrier-init (block 16) ----
// coeff: out = sum_m g[m] A^m h with g derived exactly (dyadic rationals < 2^24).
// flags[m] = 1 iff any g[j] != 0 for j >= m.
__global__ __launch_bounds__(256) void prep_kernel(const float* __restrict__ W1,
                                                   __bf16* __restrict__ w1t,
                                                   const float* __restrict__ temp,
                                                   float* __restrict__ g,
                                                   int* __restrict__ flags,
                                                   unsigned* __restrict__ arrive,
                                                   unsigned* __restrict__ epoch) {
  if (blockIdx.x == 16) {
    if (threadIdx.x != 0) return;
    *arrive = 0u;
    *epoch = 0u;
    float C[KORD + 1][KORD + 1];
    for (int n = 0; n <= KORD; ++n)
      for (int k = 0; k <= KORD; ++k) C[n][k] = 0.f;
    for (int n = 0; n <= KORD; ++n) {
      C[n][0] = 1.f;
      for (int k = 1; k <= n; ++k) C[n][k] = C[n - 1][k - 1] + C[n - 1][k];
    }
    float s[KORD + 1];
    for (int j = 0; j <= KORD; ++j) {
      float th = temp[j] > 0.f ? temp[j] : 0.f;
      s[j] = C[KORD][j] * (1.0f / 1024.0f) * th;
    }
    for (int m = 0; m <= KORD; ++m) {
      float acc = 0.f;
      for (int j = 0; j <= KORD; ++j) {
        float T = 0.f;
        for (int a = 0; a <= m; ++a) {
          int b = m - a;
          if (a <= j && b <= KORD - j)
            T += ((a & 1) ? -1.f : 1.f) * C[j][a] * C[KORD - j][b];
        }
        acc += s[j] * T;
      }
      g[m] = acc;
    }
    int any = 0;
    flags[0] = 1;
    for (int m = KORD; m >= 1; --m) {
      if (g[m] != 0.f) any = 1;
      flags[m] = any;
    }
    return;
  }
  // blocks 0..15: W1 -> transposed bf16, K padded to 512: w1t[c][k]
  for (int idx = blockIdx.x * 256 + threadIdx.x; idx < HIDDIM * KPAD; idx += 16 * 256) {
    int c = idx >> 9, k = idx & (KPAD - 1);
    float v = (k < FIN) ? W1[(size_t)k * HIDDIM + c] : 0.f;
    w1t[(size_t)c * KPAD + k] = (__bf16)v;
  }
}

// ---------------- fused MLP: u,out = MLP(x); null case also writes log_softmax ----------
// R10 GEMM structure unchanged (best measured). Epilogue: when flags[1]==0 the
// propagation is an exact no-op, so out = g0*u is FINAL -> compute log_softmax
// in-register (quad-reduce via shfl_xor 1/2) and skip the dead u store.
__global__ __launch_bounds__(512, 4) void mlp_kernel(
    const float* __restrict__ x, const __bf16* __restrict__ w1t,
    const float* __restrict__ b1, const float* __restrict__ W2,
    const float* __restrict__ b2, const float* __restrict__ g,
    const int* __restrict__ flags, float* __restrict__ u, float* __restrict__ out,
    float* __restrict__ lsm, int n) {
  __shared__ __align__(16) char arena[65536];
  const int t = threadIdx.x;
  const int w = t >> 6, lane = t & 63;
  const int row0 = blockIdx.x * 128;

#pragma unroll
  for (int i = 0; i < 8; ++i) {
    int id = t + 512 * i;  // 16B chunk id, 0..4095
    int c = id >> 6, unit = id & 63;
    bf16x8 v = *(const bf16x8*)(w1t + (size_t)id * 8);
    *(bf16x8*)(arena + c * 1024 + ((unit ^ (c & 7)) << 4)) = v;
  }
  __syncthreads();

  const int arow = lane & 15;
  const int kq = lane >> 4;
  int gr = row0 + w * 16 + arow;
  if (gr > NNODES - 1) gr = NNODES - 1;
  const float* xrow = x + (size_t)gr * FIN + kq * 8;

  f32x4 acc[4] = {};
  float4 s0a, s0b, s1a, s1b, s2a, s2b, s3a, s3b;
#define LOAD_PLAIN(A, B, c_)              \
  A = *(const float4*)(xrow + (c_) * 32); \
  B = *(const float4*)(xrow + (c_) * 32 + 4);
#define LOAD_TAIL(A, B)              \
  {                                  \
    A = *(const float4*)(xrow + 480);\
    B = *(const float4*)(xrow + 484);\
    int kb = 480 + kq * 8;           \
    if (kb + 0 >= FIN) A.x = 0.f;    \
    if (kb + 1 >= FIN) A.y = 0.f;    \
    if (kb + 2 >= FIN) A.z = 0.f;    \
    if (kb + 3 >= FIN) A.w = 0.f;    \
    if (kb + 4 >= FIN) B.x = 0.f;    \
    if (kb + 5 >= FIN) B.y = 0.f;    \
    if (kb + 6 >= FIN) B.z = 0.f;    \
    if (kb + 7 >= FIN) B.w = 0.f;    \
  }
  LOAD_PLAIN(s0a, s0b, 0)
  LOAD_PLAIN(s1a, s1b, 1)
  LOAD_PLAIN(s2a, s2b, 2)
  LOAD_PLAIN(s3a, s3b, 3)

#define DO_CHUNK(c_, QA, QB)                                                      \
  {                                                                               \
    bf16x8 a;                                                                     \
    a[0] = (__bf16)QA.x; a[1] = (__bf16)QA.y; a[2] = (__bf16)QA.z;                \
    a[3] = (__bf16)QA.w; a[4] = (__bf16)QB.x; a[5] = (__bf16)QB.y;                \
    a[6] = (__bf16)QB.z; a[7] = (__bf16)QB.w;                                     \
    int uu = (c_) * 4 + kq;                                                       \
    _Pragma("unroll") for (int ct = 0; ct < 4; ++ct) {                            \
      int col = ct * 16 + arow;                                                   \
      bf16x8 b = *(const bf16x8*)(arena + col * 1024 + ((uu ^ (col & 7)) << 4));  \
      acc[ct] = __builtin_amdgcn_mfma_f32_16x16x32_bf16(a, b, acc[ct], 0, 0, 0);  \
    }                                                                             \
  }

  DO_CHUNK(0, s0a, s0b)  LOAD_PLAIN(s0a, s0b, 4)
  DO_CHUNK(1, s1a, s1b)  LOAD_PLAIN(s1a, s1b, 5)
  DO_CHUNK(2, s2a, s2b)  LOAD_PLAIN(s2a, s2b, 6)
  DO_CHUNK(3, s3a, s3b)  LOAD_PLAIN(s3a, s3b, 7)
  DO_CHUNK(4, s0a, s0b)  LOAD_PLAIN(s0a, s0b, 8)
  DO_CHUNK(5, s1a, s1b)  LOAD_PLAIN(s1a, s1b, 9)
  DO_CHUNK(6, s2a, s2b)  LOAD_PLAIN(s2a, s2b, 10)
  DO_CHUNK(7, s3a, s3b)  LOAD_PLAIN(s3a, s3b, 11)
  DO_CHUNK(8, s0a, s0b)  LOAD_PLAIN(s0a, s0b, 12)
  DO_CHUNK(9, s1a, s1b)  LOAD_PLAIN(s1a, s1b, 13)
  DO_CHUNK(10, s2a, s2b) LOAD_PLAIN(s2a, s2b, 14)
  DO_CHUNK(11, s3a, s3b) LOAD_TAIL(s3a, s3b)
  DO_CHUNK(12, s0a, s0b)
  DO_CHUNK(13, s1a, s1b)
  DO_CHUNK(14, s2a, s2b)
  DO_CHUNK(15, s3a, s3b)
#undef DO_CHUNK
#undef LOAD_PLAIN
#undef LOAD_TAIL

  __syncthreads();  // all w1t LDS reads done; arena reused below

  float* hs = (float*)arena;             // [128][66]
  float* w2s = (float*)(arena + 36864);  // [64][40]
  for (int i = t; i < HIDDIM * NCLS; i += 512) w2s[i] = W2[i];
  {
#pragma unroll
    for (int ct = 0; ct < 4; ++ct) {
      float bv = b1[ct * 16 + arow];
#pragma unroll
      for (int reg = 0; reg < 4; ++reg) {
        int rrow = w * 16 + kq * 4 + reg;
        float v = acc[ct][reg] + bv;
        hs[rrow * 66 + ct * 16 + arow] = v > 0.f ? v : 0.f;
      }
    }
  }
  __syncthreads();

  // GEMM2: 128 rows x 40 cols; thread -> (row, 10-col group); quads share a row
  int row = t >> 2, cg = (t & 3) * 10;
  float o[10] = {};
  for (int k = 0; k < HIDDIM; ++k) {
    float a = hs[row * 66 + k];
#pragma unroll
    for (int j = 0; j < 10; ++j) o[j] += a * w2s[k * 40 + cg + j];
  }
  int gr2 = row0 + row;
  if (gr2 < n) {
    float g0 = g[0];
    int active = flags[1];  // uniform across device
    float ov[10];
#pragma unroll
    for (int j = 0; j < 10; ++j) {
      float val = o[j] + b2[cg + j];
      ov[j] = g0 * val;
      if (active) u[(size_t)gr2 * NCLS + cg + j] = val;
    }
    float* orow = out + (size_t)gr2 * NCLS + cg;
#pragma unroll
    for (int j = 0; j < 10; ++j) orow[j] = ov[j];
    if (!active) {
      // out is final: fused log_softmax. Quad (t&~3..+3) holds the full row.
      float mx = ov[0];
#pragma unroll
      for (int j = 1; j < 10; ++j) mx = fmaxf(mx, ov[j]);
      mx = fmaxf(mx, __shfl_xor(mx, 1));
      mx = fmaxf(mx, __shfl_xor(mx, 2));
      float sum = 0.f;
#pragma unroll
      for (int j = 0; j < 10; ++j) sum += expf(ov[j] - mx);
      sum += __shfl_xor(sum, 1);
      sum += __shfl_xor(sum, 2);
      float lse = logf(sum);
      float* lrow = lsm + (size_t)gr2 * NCLS + cg;
#pragma unroll
      for (int j = 0; j < 10; ++j) lrow[j] = ov[j] - mx - lse;
    }
  }
}

// ---------------- fused propagation: CSR build + 10 SpMV steps + log_softmax ----------
// All blocks co-resident (208 <= 256 CUs); grid barriers sequence the phases.
// Null path (flags[1]==0, the benchmark case): immediate uniform return (mlp
// already wrote lsm). Active path ends with the lsm phase.
__global__ __launch_bounds__(256) void prop_kernel(
    const int* __restrict__ src, const int* __restrict__ dst, int E,
    int* __restrict__ cnt_dst, int* __restrict__ tmpc, int* __restrict__ deg_i,
    int* __restrict__ rowptr, int* __restrict__ col, float* __restrict__ dis,
    float* __restrict__ ua, float* __restrict__ lsm, float* __restrict__ out,
    const float* __restrict__ g, const int* __restrict__ flags,
    unsigned* __restrict__ arrive, unsigned* __restrict__ epoch) {
  if (flags[1] == 0) return;
  const int t = threadIdx.x;
  const int nb = gridDim.x;
  const int gid = blockIdx.x * 256 + t;
  const int gstride = nb * 256;
  unsigned e = 0;

  // phase 0: zero cnt_dst/tmpc/deg_i (contiguous 300000 ints)
  for (int i = gid; i < 300000; i += gstride) cnt_dst[i] = 0;
  gbar(arrive, epoch, nb, ++e);

  // phase 1: degree counts
  for (int ed = gid; ed < E; ed += gstride) {
    atomicAdd(&deg_i[src[ed]], 1);
    atomicAdd(&cnt_dst[dst[ed]], 1);
  }
  gbar(arrive, epoch, nb, ++e);

  // phase 2: dis (all blocks) + exclusive scan -> rowptr (block 0)
  for (int i = gid; i < NNODES; i += gstride) {
    int d = deg_i[i];
    dis[i] = d > 0 ? 1.0f / sqrtf((float)d) : 0.f;
  }
  if (blockIdx.x == 0) {
    __shared__ int part[256];
    const int chunk = (NNODES + 255) / 256;  // 391
    int lo = t * chunk, hi = lo + chunk;
    if (hi > NNODES) hi = NNODES;
    int s = 0;
    for (int i = lo; i < hi; ++i) s += cnt_dst[i];
    part[t] = s;
    __syncthreads();
    for (int off = 1; off < 256; off <<= 1) {
      int v = (t >= off) ? part[t - off] : 0;
      __syncthreads();
      part[t] += v;
      __syncthreads();
    }
    int run = (t > 0) ? part[t - 1] : 0;
    for (int i = lo; i < hi; ++i) {
      rowptr[i] = run;
      run += cnt_dst[i];
    }
    if (t == 255) rowptr[NNODES] = run;
  }
  gbar(arrive, epoch, nb, ++e);

  // phase 3: CSR fill (dst-major)
  for (int ed = gid; ed < E; ed += gstride) {
    int d = dst[ed];
    int pos = rowptr[d] + atomicAdd(&tmpc[d], 1);
    col[pos] = src[ed];
  }
  gbar(arrive, epoch, nb, ++e);

  // phases 4..: SpMV steps m = 1..KORD, wave per node, lanes 0..39 = features
  const int lane = t & 63;
  const int wid0 = blockIdx.x * 4 + (t >> 6);
  const int wstride = nb * 4;
  for (int m = 1; m <= KORD; ++m) {
    if (flags[m] == 0) break;  // uniform across device
    float* uin = (m & 1) ? ua : lsm;
    float* uout = (m & 1) ? lsm : ua;
    if (lane < NCLS) {
      float gm = g[m];
      for (int wid = wid0; wid < NNODES; wid += wstride) {
        int lo = rowptr[wid], hi = rowptr[wid + 1];
        float acc = 0.f;
        for (int ee = lo; ee < hi; ++ee) {
          int s = col[ee];
          acc += dis[s] * uin[(size_t)s * NCLS + lane];
        }
        acc *= dis[wid];
        size_t idx = (size_t)wid * NCLS + lane;
        uout[idx] = acc;
        out[idx] += gm * acc;
      }
    }
    gbar(arrive, epoch, nb, ++e);
  }

  // final phase: log_softmax over the completed out (wave per row)
  for (int wid = wid0; wid < NNODES; wid += wstride) {
    float xv = (lane < NCLS) ? out[(size_t)wid * NCLS + lane] : -INFINITY;
    float mx = xv;
#pragma unroll
    for (int off = 32; off; off >>= 1) mx = fmaxf(mx, __shfl_xor(mx, off));
    float ex = (lane < NCLS) ? expf(xv - mx) : 0.f;
    float sum = ex;
#pragma unroll
    for (int off = 32; off; off >>= 1) sum += __shfl_xor(sum, off);
    float lse = logf(sum);
    if (lane < NCLS) lsm[(size_t)wid * NCLS + lane] = xv - mx - lse;
  }
}

extern "C" void kernel_launch(void* const* d_in, const int* in_sizes, int n_in,
                              void* d_out, int out_size, void* d_ws, size_t ws_size,
                              hipStream_t stream) {
  (void)n_in; (void)out_size; (void)ws_size;
  const float* x = (const float*)d_in[0];
  const int* ei = (const int*)d_in[1];
  const float* W1 = (const float*)d_in[2];
  const float* b1 = (const float*)d_in[3];
  const float* W2 = (const float*)d_in[4];
  const float* b2 = (const float*)d_in[5];
  const float* temp = (const float*)d_in[6];
  int E = in_sizes[1] / 2;
  const int* src = ei;
  const int* dst = ei + E;
  int n = NNODES;

  // ws layout in 4-byte words; total ~7.72M words (~30.9 MB)
  float* ws = (float*)d_ws;
  float* ua = ws;                             // 4,000,000 f32
  int* col = (int*)(ws + 4000000);            // 3,200,000 i32
  int* cnt_dst = (int*)(ws + 7200000);        // 100,000 i32 (zeroed with next two)
  int* tmpc = (int*)(ws + 7300000);           // 100,000 i32
  int* deg_i = (int*)(ws + 7400000);          // 100,000 i32
  int* rowptr = (int*)(ws + 7500000);         // 100,001 i32
  float* dis = ws + 7600016;                  // 100,000 f32
  float* g = ws + 7700016;                    // 16 f32
  int* flags = (int*)(ws + 7700032);          // 16 i32
  unsigned* arrive = (unsigned*)(ws + 7700048);  // 1 u32
  unsigned* epoch = (unsigned*)(ws + 7700049);  // 1 u32
  __bf16* w1t = (__bf16*)(ws + 7700064);      // 32,768 bf16 = 16,384 words

  float* lsm = (float*)d_out;            // n*40, also ping-pong scratch during prop
  float* out = (float*)d_out + 4000000;  // n*40 accumulator, final output 1

  prep_kernel<<<17, 256, 0, stream>>>(W1, w1t, temp, g, flags, arrive, epoch);
  mlp_kernel<<<(n + 127) / 128, 512, 0, stream>>>(x, w1t, b1, W2, b2, g, flags, ua, out,
                                                  lsm, n);
  prop_kernel<<<208, 256, 0, stream>>>(src, dst, E, cnt_dst, tmpc, deg_i, rowptr, col,
                                       dis, ua, lsm, out, g, flags, arrive, epoch);
}